// Round 2
// baseline (322.291 us; speedup 1.0000x reference)
//
#include <hip/hip_runtime.h>

#define B_ 16
#define P_ 65536
#define T_ 64

// ---------------------------------------------------------------------------
// Kernel A: per (b, truth) argmax of IoU over all P anchors.
// Packed key: (float_bits(iou) << 32) | (0xFFFFFFFF - p)
//   - iou >= 0 so float bits are monotone
//   - tie on iou -> smaller p wins (matches jnp.argmax first-occurrence)
// Grid: (P/2048, B), block 256, 8 anchors per thread held in registers.
// ---------------------------------------------------------------------------
__global__ __launch_bounds__(256) void kA(const float4* __restrict__ anchors,
                                          const float4* __restrict__ targets,
                                          unsigned long long* __restrict__ best) {
    const int b    = blockIdx.y;
    const int tid  = threadIdx.x;
    const int base = blockIdx.x * (256 * 8);

    __shared__ float4 tt[T_];
    __shared__ float  ta[T_];
    if (tid < T_) {
        float4 t = targets[b * T_ + tid];
        tt[tid] = t;
        ta[tid] = (t.z - t.x) * (t.w - t.y);
    }

    float4 a[8];
    float  aa[8];
#pragma unroll
    for (int i = 0; i < 8; ++i) {
        int p = base + i * 256 + tid;                 // coalesced
        a[i]  = anchors[(size_t)b * P_ + p];
        aa[i] = (a[i].z - a[i].x) * (a[i].w - a[i].y);
    }
    __syncthreads();

    __shared__ unsigned long long wmax[4];
    for (int t = 0; t < T_; ++t) {
        const float4 tb = tt[t];
        const float  at = ta[t];
        unsigned long long k = 0ull;
#pragma unroll
        for (int i = 0; i < 8; ++i) {
            float lx = fmaxf(tb.x, a[i].x), ly = fmaxf(tb.y, a[i].y);
            float rx = fminf(tb.z, a[i].z), ry = fminf(tb.w, a[i].w);
            float w = fmaxf(rx - lx, 0.0f), h = fmaxf(ry - ly, 0.0f);
            float inter = w * h;
            float iou   = inter / (at + aa[i] - inter);
            unsigned p  = (unsigned)(base + i * 256 + tid);
            unsigned long long key =
                ((unsigned long long)__float_as_uint(iou) << 32) |
                (unsigned long long)(0xFFFFFFFFu - p);
            k = (k > key) ? k : key;
        }
#pragma unroll
        for (int off = 32; off; off >>= 1) {
            unsigned long long o = __shfl_down(k, off, 64);
            k = (k > o) ? k : o;
        }
        if ((tid & 63) == 0) wmax[tid >> 6] = k;
        __syncthreads();
        if (tid == 0) {
            unsigned long long m = wmax[0];
            m = (m > wmax[1]) ? m : wmax[1];
            m = (m > wmax[2]) ? m : wmax[2];
            m = (m > wmax[3]) ? m : wmax[3];
            atomicMax(&best[b * T_ + t], m);
        }
        __syncthreads();
    }
}

__device__ __forceinline__ float sl1(float d) {
    float ad = fabsf(d);
    return (ad < 1.0f) ? 0.5f * ad * ad : ad - 0.5f;
}

// ---------------------------------------------------------------------------
// Kernel B: per-anchor best-truth argmax, force-match, CE + smooth-L1.
// Grid: (P/256, B), block 256, 1 anchor per thread.
// acc[0]=loss_l sum, acc[1]=positive count, acc[2]=ce sum
// ---------------------------------------------------------------------------
__global__ __launch_bounds__(256) void kB(const float4* __restrict__ loc,
                                          const float2* __restrict__ conf,
                                          const float4* __restrict__ anchors,
                                          const float4* __restrict__ targets,
                                          const unsigned long long* __restrict__ best,
                                          float* __restrict__ acc) {
    const int b   = blockIdx.y;
    const int tid = threadIdx.x;
    const int p   = blockIdx.x * 256 + tid;

    __shared__ float4   tt[T_];
    __shared__ float    ta[T_];
    __shared__ unsigned bp[T_];
    if (tid < T_) {
        float4 t = targets[b * T_ + tid];
        tt[tid] = t;
        ta[tid] = (t.z - t.x) * (t.w - t.y);
        bp[tid] = 0xFFFFFFFFu - (unsigned)(best[b * T_ + tid] & 0xFFFFFFFFull);
    }
    __syncthreads();

    const float4 a  = anchors[(size_t)b * P_ + p];
    const float  aa = (a.z - a.x) * (a.w - a.y);

    // best truth per anchor: ascending t, strict > keeps first occurrence of max
    float bov = -1.0f;
    int   bt  = 0;
    for (int t = 0; t < T_; ++t) {
        const float4 tb = tt[t];
        float lx = fmaxf(tb.x, a.x), ly = fmaxf(tb.y, a.y);
        float rx = fminf(tb.z, a.z), ry = fminf(tb.w, a.w);
        float w = fmaxf(rx - lx, 0.0f), h = fmaxf(ry - ly, 0.0f);
        float inter = w * h;
        float iou   = inter / (ta[t] + aa - inter);
        if (iou > bov) { bov = iou; bt = t; }
    }

    // force-match: last t wins (sequential / numpy scatter semantics)
#pragma unroll
    for (int t = 0; t < T_; ++t)
        if (bp[t] == (unsigned)p) { bov = 2.0f; bt = t; }

    const int lab = (bov >= 0.5f) ? 1 : 0;

    // cross-entropy over 2 classes for every anchor
    const float2 c  = conf[(size_t)b * P_ + p];
    float mx  = fmaxf(c.x, c.y);
    float lse = mx + logf(expf(c.x - mx) + expf(c.y - mx));
    float ce  = lse - (lab ? c.y : c.x);

    float ll = 0.0f, cn = 0.0f;
    if (lab) {
        const float4 m  = tt[bt];
        float acx = (a.x + a.z) * 0.5f, acy = (a.y + a.w) * 0.5f;
        float aw  = a.z - a.x,          ah  = a.w - a.y;
        float mcx = (m.x + m.z) * 0.5f, mcy = (m.y + m.w) * 0.5f;
        float mw  = m.z - m.x,          mh  = m.w - m.y;
        float g0 = (mcx - acx) / (0.1f * aw);
        float g1 = (mcy - acy) / (0.1f * ah);
        float g2 = logf(mw / aw) / 0.2f;
        float g3 = logf(mh / ah) / 0.2f;
        const float4 l = loc[(size_t)b * P_ + p];
        ll = sl1(l.x - g0) + sl1(l.y - g1) + sl1(l.z - g2) + sl1(l.w - g3);
        cn = 1.0f;
    }

    // block reduction of the three partials
#pragma unroll
    for (int off = 32; off; off >>= 1) {
        ll += __shfl_down(ll, off, 64);
        cn += __shfl_down(cn, off, 64);
        ce += __shfl_down(ce, off, 64);
    }
    __shared__ float r[3][4];
    const int lane = tid & 63, w = tid >> 6;
    if (lane == 0) { r[0][w] = ll; r[1][w] = cn; r[2][w] = ce; }
    __syncthreads();
    if (tid == 0) {
        atomicAdd(&acc[0], r[0][0] + r[0][1] + r[0][2] + r[0][3]);
        atomicAdd(&acc[1], r[1][0] + r[1][1] + r[1][2] + r[1][3]);
        atomicAdd(&acc[2], r[2][0] + r[2][1] + r[2][2] + r[2][3]);
    }
}

// ---------------------------------------------------------------------------
// Finalize: out = loss_l / cnt + ce_sum / (P * (B*P))
// ---------------------------------------------------------------------------
__global__ void kF(const float* __restrict__ acc, float* __restrict__ out) {
    double ll = (double)acc[0];
    double cn = (double)acc[1];
    double ce = (double)acc[2];
    out[0] = (float)(ll / cn + ce / ((double)P_ * (double)(B_ * P_)));
}

extern "C" void kernel_launch(void* const* d_in, const int* in_sizes, int n_in,
                              void* d_out, int out_size, void* d_ws, size_t ws_size,
                              hipStream_t stream) {
    const float4* loc     = (const float4*)d_in[0];
    const float2* conf    = (const float2*)d_in[1];
    const float4* anchors = (const float4*)d_in[2];
    const float4* targets = (const float4*)d_in[3];

    unsigned long long* best = (unsigned long long*)d_ws;
    float* acc = (float*)((char*)d_ws + (size_t)B_ * T_ * sizeof(unsigned long long));

    // ws is re-poisoned to 0xAA before every timed launch — zero what we use.
    hipMemsetAsync(d_ws, 0, (size_t)B_ * T_ * sizeof(unsigned long long) + 4 * sizeof(float), stream);

    dim3 gA(P_ / (256 * 8), B_);
    kA<<<gA, dim3(256), 0, stream>>>(anchors, targets, best);

    dim3 gB(P_ / 256, B_);
    kB<<<gB, dim3(256), 0, stream>>>(loc, conf, anchors, targets, best, acc);

    kF<<<1, 1, 0, stream>>>(acc, (float*)d_out);
}

// Round 4
// 210.160 us; speedup vs baseline: 1.5336x; 1.5336x over previous
//
#include <hip/hip_runtime.h>

#define B_ 16
#define P_ 65536
#define T_ 64
#define APT 4            // anchors per thread in k1
#define BLK 256
#define APB (APT * BLK)  // anchors per block = 1024

__device__ __forceinline__ float rcpf(float x) { return __builtin_amdgcn_rcpf(x); }

// inter/union of one (anchor, truth) pair. All ops non-contractible so k1 and
// k2 produce bit-identical values (discrete decisions must agree across kernels).
__device__ __forceinline__ void iou_iu(const float4& a, float aa, const float4& tb,
                                       float at, float& inter, float& u) {
    float lx = fmaxf(tb.x, a.x), ly = fmaxf(tb.y, a.y);
    float rx = fminf(tb.z, a.z), ry = fminf(tb.w, a.w);
    float w = fmaxf(__fsub_rn(rx, lx), 0.0f);
    float h = fmaxf(__fsub_rn(ry, ly), 0.0f);
    inter = __fmul_rn(w, h);
    u     = __fsub_rn(__fadd_rn(at, aa), inter);
}

// iou1 > iou2 without division: i1/u1 > i2/u2  <=>  i1*u2 > i2*u1 (u > 0)
__device__ __forceinline__ bool gt_iou(float i1, float u1, float i2, float u2) {
    return __fmul_rn(i1, u2) > __fmul_rn(i2, u1);
}

__device__ __forceinline__ float sl1(float d) {
    float ad = fabsf(d);
    return (ad < 1.0f) ? 0.5f * ad * ad : ad - 0.5f;
}

// smooth-L1 of loc vs SSD-encoded (truth m, anchor a)
__device__ __forceinline__ float sl1_enc(const float4& l, const float4& a, const float4& m) {
    float aw = a.z - a.x, ah = a.w - a.y;
    float acx = (a.x + a.z) * 0.5f, acy = (a.y + a.w) * 0.5f;
    float mcx = (m.x + m.z) * 0.5f, mcy = (m.y + m.w) * 0.5f;
    float mw = m.z - m.x, mh = m.w - m.y;
    float g0 = (mcx - acx) / (0.1f * aw);
    float g1 = (mcy - acy) / (0.1f * ah);
    float g2 = __logf(mw / aw) * 5.0f;   // /0.2
    float g3 = __logf(mh / ah) * 5.0f;
    return sl1(l.x - g0) + sl1(l.y - g1) + sl1(l.z - g2) + sl1(l.w - g3);
}

// ---------------------------------------------------------------------------
// k1: single pass over the T x P IoU matrix.
//  - per anchor: best truth via cross-mult compares -> label, CE, smooth-L1
//  - per truth: block-side max of packed (iou_bits<<32)|(~p) -> atomicMax
// acc[0]=loss_l, acc[1]=pos count, acc[2]=ce sum
// ---------------------------------------------------------------------------
__global__ __launch_bounds__(256) void k1(const float4* __restrict__ loc,
                                          const float2* __restrict__ conf,
                                          const float4* __restrict__ anchors,
                                          const float4* __restrict__ targets,
                                          unsigned long long* __restrict__ best,
                                          float* __restrict__ acc) {
    const int b    = blockIdx.y;
    const int tid  = threadIdx.x;
    const int base = blockIdx.x * APB;

    __shared__ float4 tt[T_];
    __shared__ float  ta[T_];
    if (tid < T_) {
        float4 t = targets[b * T_ + tid];
        tt[tid] = t;
        ta[tid] = (t.z - t.x) * (t.w - t.y);
    }
    __syncthreads();

    float4 a[APT]; float aa[APT]; int p[APT];
#pragma unroll
    for (int i = 0; i < APT; ++i) {
        p[i]  = base + i * BLK + tid;                 // coalesced
        a[i]  = anchors[(size_t)b * P_ + p[i]];
        aa[i] = (a[i].z - a[i].x) * (a[i].w - a[i].y);
    }

    // per-anchor running best over truths as (inter, union) pair
    float ib[APT], ub[APT]; int bt[APT];
#pragma unroll
    for (int i = 0; i < APT; ++i) { ib[i] = 0.0f; ub[i] = 1.0f; bt[i] = 0; }

    for (int t = 0; t < T_; ++t) {
        const float4 tb = tt[t];
        const float  at = ta[t];
        float li = 0.0f, lu = 1.0f; int lp = 0;       // thread-local best for this truth
#pragma unroll
        for (int i = 0; i < APT; ++i) {
            float inter, u;
            iou_iu(a[i], aa[i], tb, at, inter, u);
            // ascending t + strict > == jnp.argmax first-occurrence over truths
            if (gt_iou(inter, u, ib[i], ub[i])) { ib[i] = inter; ub[i] = u; bt[i] = t; }
            // ascending p within thread + strict > == smaller p on ties
            if (gt_iou(inter, u, li, lu)) { li = inter; lu = u; lp = p[i]; }
        }
        // one rcp per (wave-lane, truth); pack for cross-block atomic argmax
        float iou = __fmul_rn(li, rcpf(lu));
        unsigned long long key =
            ((unsigned long long)__float_as_uint(iou) << 32) |
            (unsigned long long)(0xFFFFFFFFu - (unsigned)lp);
#pragma unroll
        for (int off = 32; off; off >>= 1) {
            unsigned long long o = __shfl_down(key, off, 64);
            key = (o > key) ? o : key;
        }
        if ((tid & 63) == 0) atomicMax(&best[b * T_ + t], key);
    }

    // per-anchor losses (pre-force-match; fixup kernel corrects forced anchors)
    float ll = 0.0f, cn = 0.0f, ces = 0.0f;
#pragma unroll
    for (int i = 0; i < APT; ++i) {
        float bov = __fmul_rn(ib[i], rcpf(ub[i]));
        int lab = (bov >= 0.5f);
        float2 c = conf[(size_t)b * P_ + p[i]];
        float mx  = fmaxf(c.x, c.y);
        float lse = mx + __logf(__expf(c.x - mx) + __expf(c.y - mx));
        ces += lse - (lab ? c.y : c.x);
        if (lab) {
            float4 l = loc[(size_t)b * P_ + p[i]];
            ll += sl1_enc(l, a[i], tt[bt[i]]);
            cn += 1.0f;
        }
    }
#pragma unroll
    for (int off = 32; off; off >>= 1) {
        ll  += __shfl_down(ll,  off, 64);
        cn  += __shfl_down(cn,  off, 64);
        ces += __shfl_down(ces, off, 64);
    }
    __shared__ float r[3][4];
    const int lane = tid & 63, w = tid >> 6;
    if (lane == 0) { r[0][w] = ll; r[1][w] = cn; r[2][w] = ces; }
    __syncthreads();
    if (tid == 0) {
        atomicAdd(&acc[0], r[0][0] + r[0][1] + r[0][2] + r[0][3]);
        atomicAdd(&acc[1], r[1][0] + r[1][1] + r[1][2] + r[1][3]);
        atomicAdd(&acc[2], r[2][0] + r[2][1] + r[2][2] + r[2][3]);
    }
}

// ---------------------------------------------------------------------------
// k2: force-match fixup. One block per image, one thread per truth.
// For each unique forced anchor (last truth wins on duplicates), recompute its
// pre-force state bit-identically to k1 and apply the loss delta.
// ---------------------------------------------------------------------------
__global__ __launch_bounds__(64) void k2(const float4* __restrict__ loc,
                                         const float2* __restrict__ conf,
                                         const float4* __restrict__ anchors,
                                         const float4* __restrict__ targets,
                                         const unsigned long long* __restrict__ best,
                                         float* __restrict__ acc) {
    const int b = blockIdx.x, t = threadIdx.x;
    __shared__ float4   tt[T_];
    __shared__ float    ta[T_];
    __shared__ unsigned bp[T_];
    float4 tb0 = targets[b * T_ + t];
    tt[t] = tb0;
    ta[t] = (tb0.z - tb0.x) * (tb0.w - tb0.y);
    bp[t] = 0xFFFFFFFFu - (unsigned)(best[b * T_ + t] & 0xFFFFFFFFull);
    __syncthreads();

    // sequential scatter semantics: only the LAST truth writing this anchor sticks
    const unsigned mine = bp[t];
    for (int t2 = t + 1; t2 < T_; ++t2)
        if (bp[t2] == mine) return;

    const int pidx = (int)mine;
    const float4 a  = anchors[(size_t)b * P_ + pidx];
    const float  aa = (a.z - a.x) * (a.w - a.y);

    // recompute per-anchor best exactly as k1 (same non-contractible helpers)
    float ib = 0.0f, ub = 1.0f; int bt = 0;
    for (int t2 = 0; t2 < T_; ++t2) {
        float inter, u;
        iou_iu(a, aa, tt[t2], ta[t2], inter, u);
        if (gt_iou(inter, u, ib, ub)) { ib = inter; ub = u; bt = t2; }
    }
    float bov = __fmul_rn(ib, rcpf(ub));
    int lab_old = (bov >= 0.5f);

    float2 c = conf[(size_t)b * P_ + pidx];
    float dce = (lab_old ? c.y : c.x) - c.y;   // new label is always 1
    float4 l = loc[(size_t)b * P_ + pidx];
    float dll = sl1_enc(l, a, tt[t]);
    if (lab_old) dll -= sl1_enc(l, a, tt[bt]);
    float dcn = lab_old ? 0.0f : 1.0f;

    atomicAdd(&acc[0], dll);
    atomicAdd(&acc[1], dcn);
    atomicAdd(&acc[2], dce);
}

// ---------------------------------------------------------------------------
// finalize: out = loss_l / cnt + ce_sum / (P * (B*P))
// ---------------------------------------------------------------------------
__global__ void kF(const float* __restrict__ acc, float* __restrict__ out) {
    double ll = (double)acc[0];
    double cn = (double)acc[1];
    double ce = (double)acc[2];
    out[0] = (float)(ll / cn + ce / ((double)P_ * (double)(B_ * P_)));
}

extern "C" void kernel_launch(void* const* d_in, const int* in_sizes, int n_in,
                              void* d_out, int out_size, void* d_ws, size_t ws_size,
                              hipStream_t stream) {
    const float4* loc     = (const float4*)d_in[0];
    const float2* conf    = (const float2*)d_in[1];
    const float4* anchors = (const float4*)d_in[2];
    const float4* targets = (const float4*)d_in[3];

    unsigned long long* best = (unsigned long long*)d_ws;
    float* acc = (float*)((char*)d_ws + (size_t)B_ * T_ * sizeof(unsigned long long));

    // ws is re-poisoned to 0xAA before every timed launch — zero what we use.
    hipMemsetAsync(d_ws, 0, (size_t)B_ * T_ * sizeof(unsigned long long) + 4 * sizeof(float), stream);

    dim3 g1(P_ / APB, B_);
    k1<<<g1, dim3(BLK), 0, stream>>>(loc, conf, anchors, targets, best, acc);

    k2<<<dim3(B_), dim3(T_), 0, stream>>>(loc, conf, anchors, targets, best, acc);

    kF<<<1, 1, 0, stream>>>(acc, (float*)d_out);
}

// Round 6
// 164.500 us; speedup vs baseline: 1.9592x; 1.2776x over previous
//
#include <hip/hip_runtime.h>

#define B_ 16
#define P_ 65536
#define T_ 64
#define APT 4                 // anchors per thread in k1
#define BLK 256
#define APB (APT * BLK)       // anchors per block = 1024
#define NBLK (P_ / APB)       // 64 blocks per image
#define NPART (B_ * NBLK)     // 1024 partial slots == k2 block size

__device__ __forceinline__ float rcpf(float x) { return __builtin_amdgcn_rcpf(x); }

// ---- DPP 64-lane max-reduce of a packed u64 key (zero LDS traffic) --------
// CTRL must be a compile-time constant AT THE BUILTIN CALL SITE -> template.
template <int CTRL>
__device__ __forceinline__ unsigned dpp_mov(unsigned v) {
    // old = v so out-of-range source lanes keep the current value (harmless)
    return (unsigned)__builtin_amdgcn_update_dpp((int)v, (int)v, CTRL, 0xf, 0xf, false);
}
template <int CTRL>
__device__ __forceinline__ unsigned long long dpp_key(unsigned long long k) {
    unsigned lo = dpp_mov<CTRL>((unsigned)k);
    unsigned hi = dpp_mov<CTRL>((unsigned)(k >> 32));
    return ((unsigned long long)hi << 32) | lo;
}
// After this, lane 63 holds max over all 64 lanes.
__device__ __forceinline__ unsigned long long wave_max_key(unsigned long long k) {
    unsigned long long o;
    o = dpp_key<0x111>(k); k = (o > k) ? o : k;   // row_shr:1
    o = dpp_key<0x112>(k); k = (o > k) ? o : k;   // row_shr:2
    o = dpp_key<0x114>(k); k = (o > k) ? o : k;   // row_shr:4
    o = dpp_key<0x118>(k); k = (o > k) ? o : k;   // row_shr:8
    o = dpp_key<0x142>(k); k = (o > k) ? o : k;   // row_bcast:15
    o = dpp_key<0x143>(k); k = (o > k) ? o : k;   // row_bcast:31
    return k;
}

// inter/union of one (anchor, truth) pair. Non-contractible ops so k1 and k2
// reproduce bit-identical values (discrete decisions must agree across kernels).
__device__ __forceinline__ void iou_iu(const float4& a, float aa, const float4& tb,
                                       float at, float& inter, float& u) {
    float lx = fmaxf(tb.x, a.x), ly = fmaxf(tb.y, a.y);
    float rx = fminf(tb.z, a.z), ry = fminf(tb.w, a.w);
    float w = fmaxf(__fsub_rn(rx, lx), 0.0f);
    float h = fmaxf(__fsub_rn(ry, ly), 0.0f);
    inter = __fmul_rn(w, h);
    u     = __fsub_rn(__fadd_rn(at, aa), inter);
}

// iou1 > iou2 without division: i1/u1 > i2/u2  <=>  i1*u2 > i2*u1 (u > 0)
__device__ __forceinline__ bool gt_iou(float i1, float u1, float i2, float u2) {
    return __fmul_rn(i1, u2) > __fmul_rn(i2, u1);
}

__device__ __forceinline__ float sl1(float d) {
    float ad = fabsf(d);
    return (ad < 1.0f) ? 0.5f * ad * ad : ad - 0.5f;
}

// smooth-L1 of loc vs SSD-encoded (truth m, anchor a)
__device__ __forceinline__ float sl1_enc(const float4& l, const float4& a, const float4& m) {
    float aw = a.z - a.x, ah = a.w - a.y;
    float acx = (a.x + a.z) * 0.5f, acy = (a.y + a.w) * 0.5f;
    float mcx = (m.x + m.z) * 0.5f, mcy = (m.y + m.w) * 0.5f;
    float mw = m.z - m.x, mh = m.w - m.y;
    float g0 = (mcx - acx) / (0.1f * aw);
    float g1 = (mcy - acy) / (0.1f * ah);
    float g2 = __logf(mw / aw) * 5.0f;   // /0.2
    float g3 = __logf(mh / ah) * 5.0f;
    return sl1(l.x - g0) + sl1(l.y - g1) + sl1(l.z - g2) + sl1(l.w - g3);
}

// ---------------------------------------------------------------------------
// k1: one pass over the T x P IoU matrix. No atomics, no pre-zeroed memory.
//  - per anchor: best truth via cross-mult compares -> label, CE, smooth-L1
//  - per truth: DPP wave argmax of packed (iou_bits<<32)|(~p), block combine,
//    one coalesced u64[64] store per block -> best_blk
//  - per block: (loss_l, cnt, ce) partials -> part[block]
// ---------------------------------------------------------------------------
__global__ __launch_bounds__(256) void k1(const float4* __restrict__ loc,
                                          const float2* __restrict__ conf,
                                          const float4* __restrict__ anchors,
                                          const float4* __restrict__ targets,
                                          unsigned long long* __restrict__ best_blk,
                                          float4* __restrict__ part) {
    const int b    = blockIdx.y;
    const int bx   = blockIdx.x;
    const int tid  = threadIdx.x;
    const int base = bx * APB;

    __shared__ float4 tt[T_];
    __shared__ float  ta[T_];
    __shared__ unsigned long long arr[4][T_];   // per-wave, per-truth keys
    if (tid < T_) {
        float4 t = targets[b * T_ + tid];
        tt[tid] = t;
        ta[tid] = (t.z - t.x) * (t.w - t.y);
    }
    __syncthreads();

    float4 a[APT]; float aa[APT]; int p[APT];
#pragma unroll
    for (int i = 0; i < APT; ++i) {
        p[i]  = base + i * BLK + tid;            // coalesced
        a[i]  = anchors[(size_t)b * P_ + p[i]];
        aa[i] = (a[i].z - a[i].x) * (a[i].w - a[i].y);
    }

    float ib[APT], ub[APT]; int bt[APT];
#pragma unroll
    for (int i = 0; i < APT; ++i) { ib[i] = 0.0f; ub[i] = 1.0f; bt[i] = 0; }

    for (int t = 0; t < T_; ++t) {
        const float4 tb = tt[t];
        const float  at = ta[t];
        float li = 0.0f, lu = 1.0f; int lp = 0;  // lane's best anchor for truth t
#pragma unroll
        for (int i = 0; i < APT; ++i) {
            float inter, u;
            iou_iu(a[i], aa[i], tb, at, inter, u);
            // ascending t + strict > == jnp.argmax first-occurrence over truths
            if (gt_iou(inter, u, ib[i], ub[i])) { ib[i] = inter; ub[i] = u; bt[i] = t; }
            // ascending p within thread + strict > == smaller p on ties
            if (gt_iou(inter, u, li, lu)) { li = inter; lu = u; lp = p[i]; }
        }
        float iou = __fmul_rn(li, rcpf(lu));
        unsigned long long key =
            ((unsigned long long)__float_as_uint(iou) << 32) |
            (unsigned long long)(0xFFFFFFFFu - (unsigned)lp);
        key = wave_max_key(key);                 // pure VALU, no LDS
        if ((tid & 63) == 63) arr[tid >> 6][t] = key;
    }
    __syncthreads();

    if (tid < T_) {                              // block combine, coalesced store
        unsigned long long k = arr[0][tid];
        k = (arr[1][tid] > k) ? arr[1][tid] : k;
        k = (arr[2][tid] > k) ? arr[2][tid] : k;
        k = (arr[3][tid] > k) ? arr[3][tid] : k;
        best_blk[(size_t)(b * NBLK + bx) * T_ + tid] = k;
    }

    // per-anchor losses (pre-force-match; k2 applies force-match deltas)
    float ll = 0.0f, cn = 0.0f, ces = 0.0f;
#pragma unroll
    for (int i = 0; i < APT; ++i) {
        // exact threshold: ib/ub >= 0.5  <=>  2*ib >= ub
        int lab = (__fmul_rn(2.0f, ib[i]) >= ub[i]);
        float2 c = conf[(size_t)b * P_ + p[i]];
        float mx  = fmaxf(c.x, c.y);
        float lse = mx + __logf(__expf(c.x - mx) + __expf(c.y - mx));
        ces += lse - (lab ? c.y : c.x);
        if (lab) {
            float4 l = loc[(size_t)b * P_ + p[i]];
            ll += sl1_enc(l, a[i], tt[bt[i]]);
            cn += 1.0f;
        }
    }
#pragma unroll
    for (int off = 32; off; off >>= 1) {
        ll  += __shfl_down(ll,  off, 64);
        cn  += __shfl_down(cn,  off, 64);
        ces += __shfl_down(ces, off, 64);
    }
    __shared__ float r[3][4];
    const int lane = tid & 63, w = tid >> 6;
    if (lane == 0) { r[0][w] = ll; r[1][w] = cn; r[2][w] = ces; }
    __syncthreads();
    if (tid == 0) {
        part[b * NBLK + bx] = make_float4(r[0][0] + r[0][1] + r[0][2] + r[0][3],
                                          r[1][0] + r[1][1] + r[1][2] + r[1][3],
                                          r[2][0] + r[2][1] + r[2][2] + r[2][3], 0.0f);
    }
}

// ---------------------------------------------------------------------------
// k2: single block, 1024 threads = (b, t) pairs. Reduces block keys and loss
// partials, applies force-match fixup deltas, writes the final scalar.
// ---------------------------------------------------------------------------
__global__ __launch_bounds__(1024) void k2(const float4* __restrict__ loc,
                                           const float2* __restrict__ conf,
                                           const float4* __restrict__ anchors,
                                           const float4* __restrict__ targets,
                                           const unsigned long long* __restrict__ best_blk,
                                           const float4* __restrict__ part,
                                           float* __restrict__ out) {
    const int tid = threadIdx.x;
    const int b = tid >> 6, t = tid & 63;

    __shared__ float4   tt[B_][T_];
    __shared__ float    ta[B_][T_];
    __shared__ unsigned bp[B_][T_];
    __shared__ float    red[3][16];
    __shared__ float    dacc[3];
    if (tid < 3) dacc[tid] = 0.0f;

    float4 tb0 = targets[tid];
    tt[b][t] = tb0;
    ta[b][t] = (tb0.z - tb0.x) * (tb0.w - tb0.y);

    // final per-truth argmax over the 64 block keys (coalesced u64 loads)
    unsigned long long k = 0ull;
    for (int blk = 0; blk < NBLK; ++blk) {
        unsigned long long o = best_blk[(size_t)(b * NBLK + blk) * T_ + t];
        k = (o > k) ? o : k;
    }
    bp[b][t] = 0xFFFFFFFFu - (unsigned)(k & 0xFFFFFFFFull);

    // reduce the 1024 per-block loss partials (one float4 per thread)
    float4 pr = part[tid];
    float ll = pr.x, cn = pr.y, ces = pr.z;
#pragma unroll
    for (int off = 32; off; off >>= 1) {
        ll  += __shfl_down(ll,  off, 64);
        cn  += __shfl_down(cn,  off, 64);
        ces += __shfl_down(ces, off, 64);
    }
    if ((tid & 63) == 0) { red[0][tid >> 6] = ll; red[1][tid >> 6] = cn; red[2][tid >> 6] = ces; }
    __syncthreads();

    // force-match fixup: sequential scatter semantics -> last truth wins
    float dll = 0.0f, dcn = 0.0f, dce = 0.0f;
    const unsigned mine = bp[b][t];
    bool dup = false;
    for (int t2 = t + 1; t2 < T_; ++t2) dup |= (bp[b][t2] == mine);
    if (!dup) {
        const int pidx = (int)mine;
        const float4 a  = anchors[(size_t)b * P_ + pidx];
        const float  aa = (a.z - a.x) * (a.w - a.y);
        float ibv = 0.0f, ubv = 1.0f; int btv = 0;
        for (int t2 = 0; t2 < T_; ++t2) {        // bit-identical to k1's decisions
            float inter, u;
            iou_iu(a, aa, tt[b][t2], ta[b][t2], inter, u);
            if (gt_iou(inter, u, ibv, ubv)) { ibv = inter; ubv = u; btv = t2; }
        }
        int lab_old = (__fmul_rn(2.0f, ibv) >= ubv);
        float2 c = conf[(size_t)b * P_ + pidx];
        dce = (lab_old ? c.y : c.x) - c.y;       // new label is always 1
        float4 l = loc[(size_t)b * P_ + pidx];
        dll = sl1_enc(l, a, tt[b][t]);
        if (lab_old) dll -= sl1_enc(l, a, tt[b][btv]);
        dcn = lab_old ? 0.0f : 1.0f;
    }
#pragma unroll
    for (int off = 32; off; off >>= 1) {
        dll += __shfl_down(dll, off, 64);
        dcn += __shfl_down(dcn, off, 64);
        dce += __shfl_down(dce, off, 64);
    }
    if ((tid & 63) == 0) {
        atomicAdd(&dacc[0], dll);
        atomicAdd(&dacc[1], dcn);
        atomicAdd(&dacc[2], dce);
    }
    __syncthreads();

    if (tid == 0) {
        double L = 0.0, C = 0.0, E = 0.0;
        for (int w = 0; w < 16; ++w) { L += red[0][w]; C += red[1][w]; E += red[2][w]; }
        L += dacc[0]; C += dacc[1]; E += dacc[2];
        out[0] = (float)(L / C + E / ((double)P_ * (double)(B_ * P_)));
    }
}

extern "C" void kernel_launch(void* const* d_in, const int* in_sizes, int n_in,
                              void* d_out, int out_size, void* d_ws, size_t ws_size,
                              hipStream_t stream) {
    const float4* loc     = (const float4*)d_in[0];
    const float2* conf    = (const float2*)d_in[1];
    const float4* anchors = (const float4*)d_in[2];
    const float4* targets = (const float4*)d_in[3];

    // ws layout (no zeroing needed; k1 writes every slot before k2 reads):
    //   [0, 512K)    best_blk: u64[B*NBLK*T]
    //   [512K, 528K) part:     float4[NPART]
    unsigned long long* best_blk = (unsigned long long*)d_ws;
    float4* part = (float4*)((char*)d_ws + (size_t)B_ * NBLK * T_ * sizeof(unsigned long long));

    dim3 g1(NBLK, B_);
    k1<<<g1, dim3(BLK), 0, stream>>>(loc, conf, anchors, targets, best_blk, part);

    k2<<<dim3(1), dim3(1024), 0, stream>>>(loc, conf, anchors, targets, best_blk, part,
                                           (float*)d_out);
}

// Round 7
// 159.172 us; speedup vs baseline: 2.0248x; 1.0335x over previous
//
#include <hip/hip_runtime.h>

#define B_ 16
#define P_ 65536
#define T_ 64
#define APT 8                 // anchors per thread in k1
#define BLK 256
#define APB (APT * BLK)       // anchors per block = 2048
#define NBLK (P_ / APB)       // 32 blocks per image
#define NPART (B_ * NBLK)     // 512 partial slots

__device__ __forceinline__ float rcpf(float x) { return __builtin_amdgcn_rcpf(x); }

// ---- DPP 64-lane reduces on u32 (pure VALU, zero LDS traffic) -------------
template <int CTRL>
__device__ __forceinline__ unsigned dpp_mov(unsigned v) {
    // old = v so out-of-range/inactive sources keep the current value
    return (unsigned)__builtin_amdgcn_update_dpp((int)v, (int)v, CTRL, 0xf, 0xf, false);
}
// After these, lane 63 holds the reduction over all 64 lanes.
__device__ __forceinline__ unsigned wave_max_u32(unsigned v) {
    unsigned o;
    o = dpp_mov<0x111>(v); v = (o > v) ? o : v;   // row_shr:1
    o = dpp_mov<0x112>(v); v = (o > v) ? o : v;   // row_shr:2
    o = dpp_mov<0x114>(v); v = (o > v) ? o : v;   // row_shr:4
    o = dpp_mov<0x118>(v); v = (o > v) ? o : v;   // row_shr:8
    o = dpp_mov<0x142>(v); v = (o > v) ? o : v;   // row_bcast:15
    o = dpp_mov<0x143>(v); v = (o > v) ? o : v;   // row_bcast:31
    return v;
}
__device__ __forceinline__ unsigned wave_min_u32(unsigned v) {
    unsigned o;
    o = dpp_mov<0x111>(v); v = (o < v) ? o : v;
    o = dpp_mov<0x112>(v); v = (o < v) ? o : v;
    o = dpp_mov<0x114>(v); v = (o < v) ? o : v;
    o = dpp_mov<0x118>(v); v = (o < v) ? o : v;
    o = dpp_mov<0x142>(v); v = (o < v) ? o : v;
    o = dpp_mov<0x143>(v); v = (o < v) ? o : v;
    return v;
}

// inter/union of one (anchor, truth) pair. Non-contractible ops so k1 and k2
// reproduce bit-identical values (discrete decisions must agree across kernels).
__device__ __forceinline__ void iou_iu(const float4& a, float aa, const float4& tb,
                                       float at, float& inter, float& u) {
    float lx = fmaxf(tb.x, a.x), ly = fmaxf(tb.y, a.y);
    float rx = fminf(tb.z, a.z), ry = fminf(tb.w, a.w);
    float w = fmaxf(__fsub_rn(rx, lx), 0.0f);
    float h = fmaxf(__fsub_rn(ry, ly), 0.0f);
    inter = __fmul_rn(w, h);
    u     = __fsub_rn(__fadd_rn(at, aa), inter);
}

// iou1 > iou2 without division: i1/u1 > i2/u2  <=>  i1*u2 > i2*u1 (u > 0)
__device__ __forceinline__ bool gt_iou(float i1, float u1, float i2, float u2) {
    return __fmul_rn(i1, u2) > __fmul_rn(i2, u1);
}

__device__ __forceinline__ float sl1(float d) {
    float ad = fabsf(d);
    return (ad < 1.0f) ? 0.5f * ad * ad : ad - 0.5f;
}

// smooth-L1 of loc vs SSD-encoded (truth m, anchor a)
__device__ __forceinline__ float sl1_enc(const float4& l, const float4& a, const float4& m) {
    float aw = a.z - a.x, ah = a.w - a.y;
    float acx = (a.x + a.z) * 0.5f, acy = (a.y + a.w) * 0.5f;
    float mcx = (m.x + m.z) * 0.5f, mcy = (m.y + m.w) * 0.5f;
    float mw = m.z - m.x, mh = m.w - m.y;
    float g0 = (mcx - acx) / (0.1f * aw);
    float g1 = (mcy - acy) / (0.1f * ah);
    float g2 = __logf(mw / aw) * 5.0f;   // /0.2
    float g3 = __logf(mh / ah) * 5.0f;
    return sl1(l.x - g0) + sl1(l.y - g1) + sl1(l.z - g2) + sl1(l.w - g3);
}

// ---------------------------------------------------------------------------
// k1: one pass over the T x P IoU matrix. No atomics, no pre-zeroed memory.
//  - per anchor: best truth via cross-mult compares -> label, CE, smooth-L1
//  - per truth: DPP u32 max of iou bits + ballot/readlane winner-index pickup
//    (exact tie -> masked DPP min of p), block combine, u64 key store
//  - per block: (loss_l, cnt, ce) partials -> part[block]
// ---------------------------------------------------------------------------
__global__ __launch_bounds__(256) void k1(const float4* __restrict__ loc,
                                          const float2* __restrict__ conf,
                                          const float4* __restrict__ anchors,
                                          const float4* __restrict__ targets,
                                          unsigned long long* __restrict__ best_blk,
                                          float4* __restrict__ part) {
    const int b    = blockIdx.y;
    const int bx   = blockIdx.x;
    const int tid  = threadIdx.x;
    const int base = bx * APB;

    __shared__ float4 tt[T_];
    __shared__ float  ta[T_];
    __shared__ unsigned long long arr[4][T_];   // per-wave, per-truth keys
    if (tid < T_) {
        float4 t = targets[b * T_ + tid];
        tt[tid] = t;
        ta[tid] = (t.z - t.x) * (t.w - t.y);
    }
    __syncthreads();

    float4 a[APT]; float aa[APT];
#pragma unroll
    for (int i = 0; i < APT; ++i) {
        a[i]  = anchors[(size_t)b * P_ + (base + i * BLK + tid)];   // coalesced
        aa[i] = (a[i].z - a[i].x) * (a[i].w - a[i].y);
    }

    float ib[APT], ub[APT]; int bt[APT];
#pragma unroll
    for (int i = 0; i < APT; ++i) { ib[i] = 0.0f; ub[i] = 1.0f; bt[i] = 0; }

#pragma unroll 2
    for (int t = 0; t < T_; ++t) {
        const float4 tb = tt[t];
        const float  at = ta[t];
        float li = 0.0f, lu = 1.0f; unsigned lp = 0u;   // lane best for truth t
#pragma unroll
        for (int i = 0; i < APT; ++i) {
            float inter, u;
            iou_iu(a[i], aa[i], tb, at, inter, u);
            // ascending t + strict > == jnp.argmax first-occurrence over truths
            if (gt_iou(inter, u, ib[i], ub[i])) { ib[i] = inter; ub[i] = u; bt[i] = t; }
            // ascending p within thread + strict > == smaller p on ties
            if (gt_iou(inter, u, li, lu)) { li = inter; lu = u; lp = (unsigned)(base + i * BLK + tid); }
        }
        unsigned bits = __float_as_uint(__fmul_rn(li, rcpf(lu)));
        unsigned m    = wave_max_u32(bits);
        unsigned smax = (unsigned)__builtin_amdgcn_readlane((int)m, 63);
        unsigned long long mask = __ballot(bits == smax);
        unsigned lpw;
        if (__popcll(mask) == 1) {                       // common case, wave-uniform
            int winner = __ffsll((long long)mask) - 1;
            lpw = (unsigned)__builtin_amdgcn_readlane((int)lp, winner);
        } else {                                         // exact tie: min p among tied
            unsigned cand = (bits == smax) ? lp : 0xFFFFFFFFu;
            unsigned mn = wave_min_u32(cand);
            lpw = (unsigned)__builtin_amdgcn_readlane((int)mn, 63);
        }
        if ((tid & 63) == 0)
            arr[tid >> 6][t] = ((unsigned long long)smax << 32) |
                               (unsigned long long)(0xFFFFFFFFu - lpw);
    }
    __syncthreads();

    if (tid < T_) {                              // block combine, coalesced store
        unsigned long long k = arr[0][tid];
        k = (arr[1][tid] > k) ? arr[1][tid] : k;
        k = (arr[2][tid] > k) ? arr[2][tid] : k;
        k = (arr[3][tid] > k) ? arr[3][tid] : k;
        best_blk[(size_t)(b * NBLK + bx) * T_ + tid] = k;
    }

    // per-anchor losses (pre-force-match; k2 applies force-match deltas)
    float ll = 0.0f, cn = 0.0f, ces = 0.0f;
#pragma unroll
    for (int i = 0; i < APT; ++i) {
        // exact threshold: ib/ub >= 0.5  <=>  2*ib >= ub
        int lab = (__fmul_rn(2.0f, ib[i]) >= ub[i]);
        float2 c = conf[(size_t)b * P_ + (base + i * BLK + tid)];
        float mx  = fmaxf(c.x, c.y);
        float lse = mx + __logf(__expf(c.x - mx) + __expf(c.y - mx));
        ces += lse - (lab ? c.y : c.x);
        if (lab) {
            float4 l = loc[(size_t)b * P_ + (base + i * BLK + tid)];
            ll += sl1_enc(l, a[i], tt[bt[i]]);
            cn += 1.0f;
        }
    }
#pragma unroll
    for (int off = 32; off; off >>= 1) {
        ll  += __shfl_down(ll,  off, 64);
        cn  += __shfl_down(cn,  off, 64);
        ces += __shfl_down(ces, off, 64);
    }
    __shared__ float r[3][4];
    const int lane = tid & 63, w = tid >> 6;
    if (lane == 0) { r[0][w] = ll; r[1][w] = cn; r[2][w] = ces; }
    __syncthreads();
    if (tid == 0) {
        part[b * NBLK + bx] = make_float4(r[0][0] + r[0][1] + r[0][2] + r[0][3],
                                          r[1][0] + r[1][1] + r[1][2] + r[1][3],
                                          r[2][0] + r[2][1] + r[2][2] + r[2][3], 0.0f);
    }
}

// ---------------------------------------------------------------------------
// k2: single block, 1024 threads = (b, t) pairs. Reduces block keys and loss
// partials, applies force-match fixup deltas, writes the final scalar.
// (~2-5 us; the measured ~85 us residual is fixed harness overhead.)
// ---------------------------------------------------------------------------
__global__ __launch_bounds__(1024) void k2(const float4* __restrict__ loc,
                                           const float2* __restrict__ conf,
                                           const float4* __restrict__ anchors,
                                           const float4* __restrict__ targets,
                                           const unsigned long long* __restrict__ best_blk,
                                           const float4* __restrict__ part,
                                           float* __restrict__ out) {
    const int tid = threadIdx.x;
    const int b = tid >> 6, t = tid & 63;

    __shared__ float4   tt[B_][T_];
    __shared__ float    ta[B_][T_];
    __shared__ unsigned bp[B_][T_];
    __shared__ float    red[3][16];
    __shared__ float    dacc[3];
    if (tid < 3) dacc[tid] = 0.0f;

    float4 tb0 = targets[tid];
    tt[b][t] = tb0;
    ta[b][t] = (tb0.z - tb0.x) * (tb0.w - tb0.y);

    // final per-truth argmax over the 32 block keys (coalesced u64 loads)
    unsigned long long k = 0ull;
    for (int blk = 0; blk < NBLK; ++blk) {
        unsigned long long o = best_blk[(size_t)(b * NBLK + blk) * T_ + t];
        k = (o > k) ? o : k;
    }
    bp[b][t] = 0xFFFFFFFFu - (unsigned)(k & 0xFFFFFFFFull);

    // reduce the 512 per-block loss partials
    float ll = 0.0f, cn = 0.0f, ces = 0.0f;
    if (tid < NPART) {
        float4 pr = part[tid];
        ll = pr.x; cn = pr.y; ces = pr.z;
    }
#pragma unroll
    for (int off = 32; off; off >>= 1) {
        ll  += __shfl_down(ll,  off, 64);
        cn  += __shfl_down(cn,  off, 64);
        ces += __shfl_down(ces, off, 64);
    }
    if ((tid & 63) == 0) { red[0][tid >> 6] = ll; red[1][tid >> 6] = cn; red[2][tid >> 6] = ces; }
    __syncthreads();

    // force-match fixup: sequential scatter semantics -> last truth wins
    float dll = 0.0f, dcn = 0.0f, dce = 0.0f;
    const unsigned mine = bp[b][t];
    bool dup = false;
    for (int t2 = t + 1; t2 < T_; ++t2) dup |= (bp[b][t2] == mine);
    if (!dup) {
        const int pidx = (int)mine;
        const float4 a  = anchors[(size_t)b * P_ + pidx];
        const float  aa = (a.z - a.x) * (a.w - a.y);
        float ibv = 0.0f, ubv = 1.0f; int btv = 0;
        for (int t2 = 0; t2 < T_; ++t2) {        // bit-identical to k1's decisions
            float inter, u;
            iou_iu(a, aa, tt[b][t2], ta[b][t2], inter, u);
            if (gt_iou(inter, u, ibv, ubv)) { ibv = inter; ubv = u; btv = t2; }
        }
        int lab_old = (__fmul_rn(2.0f, ibv) >= ubv);
        float2 c = conf[(size_t)b * P_ + pidx];
        dce = (lab_old ? c.y : c.x) - c.y;       // new label is always 1
        float4 l = loc[(size_t)b * P_ + pidx];
        dll = sl1_enc(l, a, tt[b][t]);
        if (lab_old) dll -= sl1_enc(l, a, tt[b][btv]);
        dcn = lab_old ? 0.0f : 1.0f;
    }
#pragma unroll
    for (int off = 32; off; off >>= 1) {
        dll += __shfl_down(dll, off, 64);
        dcn += __shfl_down(dcn, off, 64);
        dce += __shfl_down(dce, off, 64);
    }
    if ((tid & 63) == 0) {
        atomicAdd(&dacc[0], dll);
        atomicAdd(&dacc[1], dcn);
        atomicAdd(&dacc[2], dce);
    }
    __syncthreads();

    if (tid == 0) {
        double L = 0.0, C = 0.0, E = 0.0;
        for (int w = 0; w < 16; ++w) { L += red[0][w]; C += red[1][w]; E += red[2][w]; }
        L += dacc[0]; C += dacc[1]; E += dacc[2];
        out[0] = (float)(L / C + E / ((double)P_ * (double)(B_ * P_)));
    }
}

extern "C" void kernel_launch(void* const* d_in, const int* in_sizes, int n_in,
                              void* d_out, int out_size, void* d_ws, size_t ws_size,
                              hipStream_t stream) {
    const float4* loc     = (const float4*)d_in[0];
    const float2* conf    = (const float2*)d_in[1];
    const float4* anchors = (const float4*)d_in[2];
    const float4* targets = (const float4*)d_in[3];

    // ws layout (no zeroing needed; k1 writes every slot before k2 reads):
    //   [0, 256K)    best_blk: u64[B*NBLK*T]
    //   [256K, 264K) part:     float4[NPART]
    unsigned long long* best_blk = (unsigned long long*)d_ws;
    float4* part = (float4*)((char*)d_ws + (size_t)B_ * NBLK * T_ * sizeof(unsigned long long));

    dim3 g1(NBLK, B_);
    k1<<<g1, dim3(BLK), 0, stream>>>(loc, conf, anchors, targets, best_blk, part);

    k2<<<dim3(1), dim3(1024), 0, stream>>>(loc, conf, anchors, targets, best_blk, part,
                                           (float*)d_out);
}